// Round 1
// baseline (5331.662 us; speedup 1.0000x reference)
//
#include <hip/hip_runtime.h>

#define DIM 256
#define NH 8
#define DH 32
#define SEQ 64
#define KPAD (DH + 2)          // stride 34 floats: 8B-aligned rows, 2-way-max bank aliasing (free)
#define QSCALE 0.17677669529663687f   // 32^-0.5

// ---------------- Kernel 1: fused QKV + attention, one wave per (window, head) ----------
// Writes attention output (pre-projection) into `out` in FINAL pixel layout:
// row = global pixel index, cols = h*32 + d. Every element of out is written.
__global__ __launch_bounds__(64) void attn_stage1(
    const float* __restrict__ x, const float* __restrict__ Wq,
    const float* __restrict__ Wkv, const float* __restrict__ pos,
    float* __restrict__ out)
{
  __shared__ float ks[SEQ][KPAD];
  __shared__ float vs[SEQ][KPAD];

  const int blk = blockIdx.x;
  const int w   = blk >> 3;          // window id: 8 consecutive blocks share a window (L1/L2 reuse of x)
  const int h   = blk & 7;           // head id
  const int bi  = w >> 10;
  const int rem = w & 1023;
  const int whi = rem >> 5;
  const int wwi = rem & 31;
  const int i   = threadIdx.x;       // query row within window (0..63)
  const int gr  = whi * 8 + (i >> 3);
  const int gc  = wwi * 8 + (i & 7);
  const long prow = ((long)bi * 256 + gr) * 256 + gc;   // global pixel index
  const float* xrow = x + prow * DIM;

  // ---- QKV for this lane's row: 32 q + 32 k + 32 v accumulators ----
  float qa[DH], ka[DH], va[DH];
#pragma unroll
  for (int d = 0; d < DH; ++d) { qa[d] = 0.f; ka[d] = 0.f; va[d] = 0.f; }

  const float* wq = Wq + h * DH;            // row stride DIM
  const float* wk = Wkv + h * DH;           // row stride 2*DIM
  const float* wv = Wkv + DIM + h * DH;     // v columns live at offset DIM

  const float4* xrow4 = (const float4*)xrow;
  for (int c4 = 0; c4 < DIM / 4; ++c4) {
    float4 xv = xrow4[c4];
    float xarr[4] = {xv.x, xv.y, xv.z, xv.w};
#pragma unroll
    for (int u = 0; u < 4; ++u) {
      const int c = c4 * 4 + u;
      const float xs = xarr[u];
      const float4* wq4 = (const float4*)(wq + (size_t)c * DIM);       // wave-uniform addr
      const float4* wk4 = (const float4*)(wk + (size_t)c * (2 * DIM));
      const float4* wv4 = (const float4*)(wv + (size_t)c * (2 * DIM));
#pragma unroll
      for (int d4 = 0; d4 < DH / 4; ++d4) {
        float4 aq = wq4[d4];
        float4 ak = wk4[d4];
        float4 av = wv4[d4];
        qa[d4*4+0] += xs * aq.x; qa[d4*4+1] += xs * aq.y;
        qa[d4*4+2] += xs * aq.z; qa[d4*4+3] += xs * aq.w;
        ka[d4*4+0] += xs * ak.x; ka[d4*4+1] += xs * ak.y;
        ka[d4*4+2] += xs * ak.z; ka[d4*4+3] += xs * ak.w;
        va[d4*4+0] += xs * av.x; va[d4*4+1] += xs * av.y;
        va[d4*4+2] += xs * av.z; va[d4*4+3] += xs * av.w;
      }
    }
  }

#pragma unroll
  for (int d = 0; d < DH; ++d) {
    qa[d] *= QSCALE;
    ks[i][d] = ka[d];
    vs[i][d] = va[d];
  }
  __syncthreads();

  // ---- scores: sim[j] = q_i . k_j + pos[h][i][j] (whole row in this lane's regs) ----
  const float* ph = pos + ((size_t)h * SEQ + i) * SEQ;
  float sim[SEQ];
#pragma unroll
  for (int j = 0; j < SEQ; ++j) {
    const float2* kj = (const float2*)(&ks[j][0]);   // uniform addr -> LDS broadcast
    float s = 0.f;
#pragma unroll
    for (int d2 = 0; d2 < DH / 2; ++d2) {
      float2 kk = kj[d2];
      s += qa[d2*2+0] * kk.x;
      s += qa[d2*2+1] * kk.y;
    }
    sim[j] = s + ph[j];
  }

  // ---- softmax: all within one lane, no cross-lane reduction needed ----
  float mx = -1e30f;
#pragma unroll
  for (int j = 0; j < SEQ; ++j) mx = fmaxf(mx, sim[j]);
  float ssum = 0.f;
#pragma unroll
  for (int j = 0; j < SEQ; ++j) { float e = __expf(sim[j] - mx); sim[j] = e; ssum += e; }
  const float inv = 1.f / ssum;

  // ---- out_h[i][d] = sum_j p[j] * v[j][d] ----
  float oa[DH];
#pragma unroll
  for (int d = 0; d < DH; ++d) oa[d] = 0.f;
#pragma unroll
  for (int j = 0; j < SEQ; ++j) {
    const float pj = sim[j];
    const float2* vj = (const float2*)(&vs[j][0]);
#pragma unroll
    for (int d2 = 0; d2 < DH / 2; ++d2) {
      float2 vv = vj[d2];
      oa[d2*2+0] += pj * vv.x;
      oa[d2*2+1] += pj * vv.y;
    }
  }

  float* orow = out + prow * DIM + h * DH;
#pragma unroll
  for (int d4 = 0; d4 < DH / 4; ++d4) {
    float4 o;
    o.x = oa[d4*4+0] * inv;
    o.y = oa[d4*4+1] * inv;
    o.z = oa[d4*4+2] * inv;
    o.w = oa[d4*4+3] * inv;
    ((float4*)orow)[d4] = o;
  }
}

// ---------------- Kernel 2: in-place row projection out[p,:] = out[p,:] @ Wp + bp --------
// Block owns 64 rows; all global reads of those rows are staged into LDS before the
// barrier, stores happen after -> in-place safe; no cross-block row sharing.
#define APAD 133   // 64 x 133 floats = 34 KB; breaks the stride-128 bank pathology
__global__ __launch_bounds__(256) void proj_stage2(
    float* __restrict__ out, const float* __restrict__ Wp,
    const float* __restrict__ bp)
{
  __shared__ float a_s[SEQ][APAD];
  const long p0 = (long)blockIdx.x * SEQ;
  const int t  = threadIdx.x;
  const int mg = t >> 4;        // 0..15 -> rows mg*4 .. mg*4+3
  const int ng = t & 15;        // 0..15 -> cols ng*16 .. +15
  const int c0 = ng * 16;

  float acc[4][16];
#pragma unroll
  for (int r = 0; r < 4; ++r)
#pragma unroll
    for (int j = 0; j < 16; ++j) acc[r][j] = 0.f;

  for (int kb = 0; kb < 2; ++kb) {
    __syncthreads();
#pragma unroll
    for (int it = 0; it < 8; ++it) {
      int flat = it * 256 + t;            // 2048 float4-units = 64 rows x 128 cols
      int row  = flat >> 5;
      int c4   = flat & 31;
      float4 v = *(const float4*)(out + (p0 + row) * DIM + kb * 128 + c4 * 4);
      a_s[row][c4 * 4 + 0] = v.x;
      a_s[row][c4 * 4 + 1] = v.y;
      a_s[row][c4 * 4 + 2] = v.z;
      a_s[row][c4 * 4 + 3] = v.w;
    }
    __syncthreads();

    for (int k = 0; k < 128; ++k) {
      float av0 = a_s[mg * 4 + 0][k];
      float av1 = a_s[mg * 4 + 1][k];
      float av2 = a_s[mg * 4 + 2][k];
      float av3 = a_s[mg * 4 + 3][k];
      const float4* wr = (const float4*)(Wp + (size_t)(kb * 128 + k) * DIM + c0);
      float4 w0 = wr[0], w1 = wr[1], w2 = wr[2], w3 = wr[3];
      float wj[16] = {w0.x, w0.y, w0.z, w0.w, w1.x, w1.y, w1.z, w1.w,
                      w2.x, w2.y, w2.z, w2.w, w3.x, w3.y, w3.z, w3.w};
#pragma unroll
      for (int j = 0; j < 16; ++j) {
        acc[0][j] += av0 * wj[j];
        acc[1][j] += av1 * wj[j];
        acc[2][j] += av2 * wj[j];
        acc[3][j] += av3 * wj[j];
      }
    }
  }

  const float4* bp4 = (const float4*)(bp + c0);
  float4 b0 = bp4[0], b1 = bp4[1], b2 = bp4[2], b3 = bp4[3];
  float bj[16] = {b0.x, b0.y, b0.z, b0.w, b1.x, b1.y, b1.z, b1.w,
                  b2.x, b2.y, b2.z, b2.w, b3.x, b3.y, b3.z, b3.w};
#pragma unroll
  for (int r = 0; r < 4; ++r) {
    float* orow = out + (p0 + mg * 4 + r) * DIM + c0;
#pragma unroll
    for (int j4 = 0; j4 < 4; ++j4) {
      float4 o;
      o.x = acc[r][j4*4+0] + bj[j4*4+0];
      o.y = acc[r][j4*4+1] + bj[j4*4+1];
      o.z = acc[r][j4*4+2] + bj[j4*4+2];
      o.w = acc[r][j4*4+3] + bj[j4*4+3];
      ((float4*)orow)[j4] = o;
    }
  }
}

extern "C" void kernel_launch(void* const* d_in, const int* in_sizes, int n_in,
                              void* d_out, int out_size, void* d_ws, size_t ws_size,
                              hipStream_t stream) {
  const float* x   = (const float*)d_in[0];
  const float* Wq  = (const float*)d_in[1];
  const float* Wkv = (const float*)d_in[2];
  const float* pos = (const float*)d_in[3];
  const float* Wp  = (const float*)d_in[4];
  const float* bp  = (const float*)d_in[5];
  float* out = (float*)d_out;

  // 4096 windows x 8 heads, one wave each
  attn_stage1<<<4096 * NH, 64, 0, stream>>>(x, Wq, Wkv, pos, out);
  // 262144 rows / 64 rows per block
  proj_stage2<<<4096, 256, 0, stream>>>(out, Wp, bp);
}

// Round 2
// 1008.151 us; speedup vs baseline: 5.2886x; 5.2886x over previous
//
#include <hip/hip_runtime.h>

#define NHEADS 8
#define QSCALE 0.17677669529663687f   // 32^-0.5

typedef __attribute__((ext_vector_type(8))) short bf16x8;
typedef __attribute__((ext_vector_type(4))) float f32x4;

// LDS layout (ushort units)
#define SX   264                       // xA / attnA row stride (64 x 264)
#define QK0  16896                     // per-head q[64][40] + k[64][40]; P[64][72] overlays
#define VT0  57856                     // per-head vT[32][72]
#define SMEM_N 76288                   // 149 KB

// ws layout (ushort units): qkvT_hi[768*256] | qkvT_lo | wpT_hi[256*256] | wpT_lo
#define QKV_LO 196608
#define WP_HI  393216
#define WP_LO  458752

static __device__ __forceinline__ unsigned short f2b(float f) {
  unsigned int u = __float_as_uint(f);
  unsigned int r = u + 0x7fffu + ((u >> 16) & 1u);   // RNE
  return (unsigned short)(r >> 16);
}
static __device__ __forceinline__ float b2f(unsigned short h) {
  return __uint_as_float(((unsigned int)h) << 16);
}
static __device__ __forceinline__ f32x4 mm(bf16x8 a, bf16x8 b, f32x4 c) {
  return __builtin_amdgcn_mfma_f32_16x16x32_bf16(a, b, c, 0, 0, 0);
}

// ---------------- K0: weights -> transposed bf16 hi/lo in ws -----------------
__global__ __launch_bounds__(256) void convert_weights(
    const float* __restrict__ Wq, const float* __restrict__ Wkv,
    const float* __restrict__ Wp, unsigned short* __restrict__ ws)
{
  const int n = blockIdx.x;      // output row of transposed weight
  const int k = threadIdx.x;     // input dim
  if (n < 768) {
    float w = (n < 256) ? Wq[(size_t)k * 256 + n] * QSCALE
                        : Wkv[(size_t)k * 512 + (n - 256)];
    unsigned short hi = f2b(w);
    unsigned short lo = f2b(w - b2f(hi));
    ws[(size_t)n * 256 + k] = hi;
    ws[QKV_LO + (size_t)n * 256 + k] = lo;
  } else {
    const int n2 = n - 768;
    float w = Wp[(size_t)k * 256 + n2];
    unsigned short hi = f2b(w);
    unsigned short lo = f2b(w - b2f(hi));
    ws[WP_HI + (size_t)n2 * 256 + k] = hi;
    ws[WP_LO + (size_t)n2 * 256 + k] = lo;
  }
}

// ---------------- K1: fully fused window attention ---------------------------
// block = one 8x8 window; 8 waves; wave h owns head h end-to-end.
__global__ __launch_bounds__(512, 2) void attn_fused(
    const float* __restrict__ x, const float* __restrict__ pos,
    const unsigned short* __restrict__ ws, const float* __restrict__ bp,
    float* __restrict__ out)
{
  __shared__ __align__(16) unsigned short sm[SMEM_N];

  const int wid = blockIdx.x;
  const int bi  = wid >> 10;
  const int whi = (wid >> 5) & 31;
  const int wwi = wid & 31;
  const int t   = threadIdx.x;
  const int wv  = t >> 6;          // wave id == head id
  const int ln  = t & 63;
  const int m16 = ln & 15;
  const int q4  = ln >> 4;

  const long rowpix = ((long)bi * 256 + whi * 8) * 256 + wwi * 8;  // pixel index of window (0,0)
  const long xbase  = rowpix * 256;                                 // element offset into x/out

  // ---- Phase 0: stage x window (64 rows x 256) as bf16 into xA ----
  for (int it = 0; it < 8; ++it) {
    const int i  = it * 8 + wv;        // window row
    const int c4 = ln;                 // float4 index within row
    const float4 vx = *(const float4*)(x + xbase + (long)(i >> 3) * 65536 + (long)(i & 7) * 256 + c4 * 4);
    ushort4 b;
    b.x = f2b(vx.x); b.y = f2b(vx.y); b.z = f2b(vx.z); b.w = f2b(vx.w);
    *(ushort4*)(sm + i * SX + c4 * 4) = b;
  }
  __syncthreads();

  // ---- Phase 1: QKV for head wv (cols: q wv*32.., k 256+wv*32.., v 512+wv*32..) ----
  const unsigned short* qkvT_hi = ws;
  const unsigned short* qkvT_lo = ws + QKV_LO;
  f32x4 acc[6][4];
#pragma unroll
  for (int c = 0; c < 6; ++c)
#pragma unroll
    for (int mt = 0; mt < 4; ++mt) acc[c][mt] = (f32x4){0.f, 0.f, 0.f, 0.f};

  const int ncol[6] = {wv * 32, wv * 32 + 16, 256 + wv * 32, 256 + wv * 32 + 16,
                       512 + wv * 32, 512 + wv * 32 + 16};
#pragma unroll 2
  for (int ks = 0; ks < 8; ++ks) {
    bf16x8 af[4];
#pragma unroll
    for (int mt = 0; mt < 4; ++mt)
      af[mt] = *(const bf16x8*)(sm + (mt * 16 + m16) * SX + ks * 32 + q4 * 8);
#pragma unroll
    for (int c = 0; c < 6; ++c) {
      const size_t boff = (size_t)(ncol[c] + m16) * 256 + ks * 32 + q4 * 8;
      bf16x8 bh = *(const bf16x8*)(qkvT_hi + boff);
      bf16x8 bl = *(const bf16x8*)(qkvT_lo + boff);
#pragma unroll
      for (int mt = 0; mt < 4; ++mt) {
        acc[c][mt] = mm(af[mt], bh, acc[c][mt]);
        acc[c][mt] = mm(af[mt], bl, acc[c][mt]);
      }
    }
  }

  // park q,k (stride 40) and vT (stride 72) in wave-private LDS
  const int qh = QK0 + wv * 5120;
  const int kh = qh + 2560;
  const int vh = VT0 + wv * 2304;
#pragma unroll
  for (int c = 0; c < 6; ++c)
#pragma unroll
    for (int mt = 0; mt < 4; ++mt)
#pragma unroll
      for (int r = 0; r < 4; ++r) {
        const int i = mt * 16 + q4 * 4 + r;
        const unsigned short v = f2b(acc[c][mt][r]);
        if (c < 2)      sm[qh + i * 40 + c * 16 + m16] = v;
        else if (c < 4) sm[kh + i * 40 + (c - 2) * 16 + m16] = v;
        else            sm[vh + ((c - 4) * 16 + m16) * 72 + i] = v;
      }

  // ---- Phase 2: attention for head wv (wave-private; DS ops in-order, no barrier) ----
  bf16x8 aq[4], bk[4];
#pragma unroll
  for (int mt = 0; mt < 4; ++mt)
    aq[mt] = *(const bf16x8*)(sm + qh + (mt * 16 + m16) * 40 + q4 * 8);
#pragma unroll
  for (int nt = 0; nt < 4; ++nt)
    bk[nt] = *(const bf16x8*)(sm + kh + (nt * 16 + m16) * 40 + q4 * 8);

  f32x4 S[4][4];
#pragma unroll
  for (int mt = 0; mt < 4; ++mt)
#pragma unroll
    for (int nt = 0; nt < 4; ++nt)
      S[mt][nt] = mm(aq[mt], bk[nt], (f32x4){0.f, 0.f, 0.f, 0.f});

  const float* ph = pos + wv * 4096;
#pragma unroll
  for (int mt = 0; mt < 4; ++mt)
#pragma unroll
    for (int nt = 0; nt < 4; ++nt)
#pragma unroll
      for (int r = 0; r < 4; ++r)
        S[mt][nt][r] += ph[(mt * 16 + q4 * 4 + r) * 64 + nt * 16 + m16];

  // softmax per row (rows live across the 16 lanes of a quad) ; P overlays q/k
  const int phh = qh;                    // P[64][72]
#pragma unroll
  for (int mt = 0; mt < 4; ++mt)
#pragma unroll
    for (int r = 0; r < 4; ++r) {
      float v0 = S[mt][0][r], v1 = S[mt][1][r], v2 = S[mt][2][r], v3 = S[mt][3][r];
      float mx = fmaxf(fmaxf(v0, v1), fmaxf(v2, v3));
      mx = fmaxf(mx, __shfl_xor(mx, 1));
      mx = fmaxf(mx, __shfl_xor(mx, 2));
      mx = fmaxf(mx, __shfl_xor(mx, 4));
      mx = fmaxf(mx, __shfl_xor(mx, 8));
      v0 = __expf(v0 - mx); v1 = __expf(v1 - mx);
      v2 = __expf(v2 - mx); v3 = __expf(v3 - mx);
      float s = v0 + v1 + v2 + v3;
      s += __shfl_xor(s, 1);
      s += __shfl_xor(s, 2);
      s += __shfl_xor(s, 4);
      s += __shfl_xor(s, 8);
      const float inv = 1.0f / s;
      const int i = mt * 16 + q4 * 4 + r;
      sm[phh + i * 72 +      m16] = f2b(v0 * inv);
      sm[phh + i * 72 + 16 + m16] = f2b(v1 * inv);
      sm[phh + i * 72 + 32 + m16] = f2b(v2 * inv);
      sm[phh + i * 72 + 48 + m16] = f2b(v3 * inv);
    }

  // PV: O = P(64x64) @ V(64x32)
  f32x4 O[4][2];
#pragma unroll
  for (int mt = 0; mt < 4; ++mt)
#pragma unroll
    for (int nt = 0; nt < 2; ++nt) O[mt][nt] = (f32x4){0.f, 0.f, 0.f, 0.f};
#pragma unroll
  for (int ksp = 0; ksp < 2; ++ksp) {
    bf16x8 ap[4], bv[2];
#pragma unroll
    for (int mt = 0; mt < 4; ++mt)
      ap[mt] = *(const bf16x8*)(sm + phh + (mt * 16 + m16) * 72 + ksp * 32 + q4 * 8);
#pragma unroll
    for (int nt = 0; nt < 2; ++nt)
      bv[nt] = *(const bf16x8*)(sm + vh + (nt * 16 + m16) * 72 + ksp * 32 + q4 * 8);
#pragma unroll
    for (int mt = 0; mt < 4; ++mt)
#pragma unroll
      for (int nt = 0; nt < 2; ++nt) O[mt][nt] = mm(ap[mt], bv[nt], O[mt][nt]);
  }

  __syncthreads();   // all waves finished reading xA -> safe to overlay with attnA

  // write attnout (bf16) into attnA (overlay of xA), cols wv*32..wv*32+31
#pragma unroll
  for (int mt = 0; mt < 4; ++mt)
#pragma unroll
    for (int nt = 0; nt < 2; ++nt)
#pragma unroll
      for (int r = 0; r < 4; ++r) {
        const int i = mt * 16 + q4 * 4 + r;
        sm[i * SX + wv * 32 + nt * 16 + m16] = f2b(O[mt][nt][r]);
      }
  __syncthreads();

  // ---- Phase 3: projection, wave wv -> out cols wv*32 .. wv*32+31 ----
  const unsigned short* wpT_hi = ws + WP_HI;
  const unsigned short* wpT_lo = ws + WP_LO;
  f32x4 acc2[4][2];
#pragma unroll
  for (int mt = 0; mt < 4; ++mt)
#pragma unroll
    for (int nt = 0; nt < 2; ++nt) acc2[mt][nt] = (f32x4){0.f, 0.f, 0.f, 0.f};

#pragma unroll 2
  for (int ks = 0; ks < 8; ++ks) {
    bf16x8 aa[4];
#pragma unroll
    for (int mt = 0; mt < 4; ++mt)
      aa[mt] = *(const bf16x8*)(sm + (mt * 16 + m16) * SX + ks * 32 + q4 * 8);
#pragma unroll
    for (int nt = 0; nt < 2; ++nt) {
      const size_t boff = (size_t)(wv * 32 + nt * 16 + m16) * 256 + ks * 32 + q4 * 8;
      bf16x8 bh = *(const bf16x8*)(wpT_hi + boff);
      bf16x8 bl = *(const bf16x8*)(wpT_lo + boff);
#pragma unroll
      for (int mt = 0; mt < 4; ++mt) {
        acc2[mt][nt] = mm(aa[mt], bh, acc2[mt][nt]);
        acc2[mt][nt] = mm(aa[mt], bl, acc2[mt][nt]);
      }
    }
  }

  const float b0 = bp[wv * 32 + m16];
  const float b1 = bp[wv * 32 + 16 + m16];
#pragma unroll
  for (int mt = 0; mt < 4; ++mt)
#pragma unroll
    for (int r = 0; r < 4; ++r) {
      const int i = mt * 16 + q4 * 4 + r;
      const long prow = rowpix + (long)(i >> 3) * 256 + (i & 7);
      out[prow * 256 + wv * 32 + m16]      = acc2[mt][0][r] + b0;
      out[prow * 256 + wv * 32 + 16 + m16] = acc2[mt][1][r] + b1;
    }
}

extern "C" void kernel_launch(void* const* d_in, const int* in_sizes, int n_in,
                              void* d_out, int out_size, void* d_ws, size_t ws_size,
                              hipStream_t stream) {
  const float* x   = (const float*)d_in[0];
  const float* Wq  = (const float*)d_in[1];
  const float* Wkv = (const float*)d_in[2];
  const float* pos = (const float*)d_in[3];
  const float* Wp  = (const float*)d_in[4];
  const float* bp  = (const float*)d_in[5];
  float* out = (float*)d_out;
  unsigned short* ws = (unsigned short*)d_ws;   // 1 MB used

  convert_weights<<<1024, 256, 0, stream>>>(Wq, Wkv, Wp, ws);
  attn_fused<<<4096, 512, 0, stream>>>(x, pos, ws, bp, out);
}